// Round 2
// baseline (4315.443 us; speedup 1.0000x reference)
//
#include <hip/hip_runtime.h>
#include <stdint.h>

typedef uint16_t u16;
typedef uint32_t u32;
typedef __attribute__((ext_vector_type(8))) __bf16 bf16x8;
typedef __attribute__((ext_vector_type(8))) short short8;
typedef __attribute__((ext_vector_type(4))) float floatx4;

// ---------- helpers ----------
__device__ __forceinline__ float bf2f(u16 u) {
  union { u32 i; float f; } v; v.i = ((u32)u) << 16; return v.f;
}
__device__ __forceinline__ u16 f2bf(float f) {
  union { float f; u32 i; } v; v.f = f;
  u32 i = v.i;
  return (u16)((i + 0x7FFFu + ((i >> 16) & 1u)) >> 16); // RTNE
}
__device__ __forceinline__ float sigm(float x) { return 1.f / (1.f + __expf(-x)); }
__device__ __forceinline__ float tanh_f(float x) {
  x = fminf(15.f, fmaxf(-15.f, x));
  float e = __expf(2.f * x);
  return (e - 1.f) / (e + 1.f);
}

// ---------- fp32 -> bf16 transpose: src[R][C] f32 -> dst[C][R] bf16 ----------
__global__ void transpose_f32_bf16(const float* __restrict__ src, u16* __restrict__ dst,
                                   int R, int C) {
  __shared__ u16 tile[32][33];
  int x = blockIdx.x * 32 + threadIdx.x;
#pragma unroll
  for (int j = 0; j < 4; ++j) {
    int y = blockIdx.y * 32 + threadIdx.y + j * 8;
    if (x < C && y < R) tile[threadIdx.y + j * 8][threadIdx.x] = f2bf(src[(size_t)y * C + x]);
  }
  __syncthreads();
  int x2 = blockIdx.y * 32 + threadIdx.x;
#pragma unroll
  for (int j = 0; j < 4; ++j) {
    int y2 = blockIdx.x * 32 + threadIdx.y + j * 8;
    if (x2 < R && y2 < C) dst[(size_t)y2 * R + x2] = tile[threadIdx.x][threadIdx.y + j * 8];
  }
}

// ---------- xp GEMM: C_bf16[M,N] = A_f32[M,K] @ BT_bf16[N,K]^T + bias_f32 ----------
// 64x64 tile, 4 waves, each wave a 32x32 quadrant. K%32==0, M,N%64==0.
__global__ __launch_bounds__(256) void gemm_a32_bt(
    const float* __restrict__ A, const u16* __restrict__ BT,
    const float* __restrict__ bias, u16* __restrict__ C,
    int M, int N, int K) {
  __shared__ __align__(16) u16 As[64 * 40];
  __shared__ __align__(16) u16 Bs[64 * 40];
  const int tid = threadIdx.x;
  const int wave = tid >> 6, lane = tid & 63;
  const int q4 = lane >> 4, n16 = lane & 15;
  const int mw = (wave >> 1) * 32, nw = (wave & 1) * 32;
  const int m0 = blockIdx.y * 64, n0 = blockIdx.x * 64;
  const int ldrow = tid >> 2, ldseg = (tid & 3) * 8;

  floatx4 acc[2][2] = {};
  for (int k0 = 0; k0 < K; k0 += 32) {
    const float* ap = A + (size_t)(m0 + ldrow) * K + k0 + ldseg;
    floatx4 a0 = *(const floatx4*)ap;
    floatx4 a1 = *(const floatx4*)(ap + 4);
    short8 s;
    s[0] = (short)f2bf(a0[0]); s[1] = (short)f2bf(a0[1]);
    s[2] = (short)f2bf(a0[2]); s[3] = (short)f2bf(a0[3]);
    s[4] = (short)f2bf(a1[0]); s[5] = (short)f2bf(a1[1]);
    s[6] = (short)f2bf(a1[2]); s[7] = (short)f2bf(a1[3]);
    *(short8*)(As + ldrow * 40 + ldseg) = s;
    *(short8*)(Bs + ldrow * 40 + ldseg) =
        *(const short8*)(BT + (size_t)(n0 + ldrow) * K + k0 + ldseg);
    __syncthreads();
#pragma unroll
    for (int mi = 0; mi < 2; ++mi) {
      bf16x8 a = *(const bf16x8*)(As + (mw + mi * 16 + n16) * 40 + q4 * 8);
#pragma unroll
      for (int ni = 0; ni < 2; ++ni) {
        bf16x8 b = *(const bf16x8*)(Bs + (nw + ni * 16 + n16) * 40 + q4 * 8);
        acc[mi][ni] = __builtin_amdgcn_mfma_f32_16x16x32_bf16(a, b, acc[mi][ni], 0, 0, 0);
      }
    }
    __syncthreads();
  }
#pragma unroll
  for (int mi = 0; mi < 2; ++mi)
#pragma unroll
    for (int ni = 0; ni < 2; ++ni) {
      int col = n0 + nw + ni * 16 + n16;
      float bv = bias[col];
#pragma unroll
      for (int r = 0; r < 4; ++r) {
        int m = m0 + mw + mi * 16 + q4 * 4 + r;
        C[(size_t)m * N + col] = f2bf(acc[mi][ni][r] + bv);
      }
    }
}

// ---------- final GEMM: C_f32[M,N] = A_bf16[M,K] @ BT_bf16[N,K]^T + bias_f32 ----------
__global__ __launch_bounds__(256) void gemm_bt_f32out(
    const u16* __restrict__ A, const u16* __restrict__ BT,
    const float* __restrict__ bias, float* __restrict__ C,
    int M, int N, int K) {
  __shared__ __align__(16) u16 As[64 * 40];
  __shared__ __align__(16) u16 Bs[64 * 40];
  const int tid = threadIdx.x;
  const int wave = tid >> 6, lane = tid & 63;
  const int q4 = lane >> 4, n16 = lane & 15;
  const int mw = (wave >> 1) * 32, nw = (wave & 1) * 32;
  const int m0 = blockIdx.y * 64, n0 = blockIdx.x * 64;
  const int ldrow = tid >> 2, ldseg = (tid & 3) * 8;

  floatx4 acc[2][2] = {};
  for (int k0 = 0; k0 < K; k0 += 32) {
    *(short8*)(As + ldrow * 40 + ldseg) =
        *(const short8*)(A + (size_t)(m0 + ldrow) * K + k0 + ldseg);
    *(short8*)(Bs + ldrow * 40 + ldseg) =
        *(const short8*)(BT + (size_t)(n0 + ldrow) * K + k0 + ldseg);
    __syncthreads();
#pragma unroll
    for (int mi = 0; mi < 2; ++mi) {
      bf16x8 a = *(const bf16x8*)(As + (mw + mi * 16 + n16) * 40 + q4 * 8);
#pragma unroll
      for (int ni = 0; ni < 2; ++ni) {
        bf16x8 b = *(const bf16x8*)(Bs + (nw + ni * 16 + n16) * 40 + q4 * 8);
        acc[mi][ni] = __builtin_amdgcn_mfma_f32_16x16x32_bf16(a, b, acc[mi][ni], 0, 0, 0);
      }
    }
    __syncthreads();
  }
#pragma unroll
  for (int mi = 0; mi < 2; ++mi)
#pragma unroll
    for (int ni = 0; ni < 2; ++ni) {
      int col = n0 + nw + ni * 16 + n16;
      float bv = bias[col];
#pragma unroll
      for (int r = 0; r < 4; ++r) {
        int m = m0 + mw + mi * 16 + q4 * 4 + r;
        C[(size_t)m * N + col] = acc[mi][ni][r] + bv;
      }
    }
}

// ---------- LSTM scan ----------
// 32 blocks x 256 threads. Block -> (batch group g in [0,4), column wg wgi in [0,8)).
// Each group: 16 batches (M=16). Each wave owns 16 h-cols x 4 gates; U fragments
// (64 cols x 512 K = 64KB) preloaded into 256 VGPRs per wave. c-state in fp32 VGPRs.
// Per-step sync: per-group monotonic counters, release add by thread 0, per-wave
// lane-0 acquire spin (agent scope -> buffer_inv -> fresh L1 before h loads).
#define T_STEPS 512
__global__ __launch_bounds__(256, 1) void lstm_scan(
    const u16* __restrict__ xp,   // [64, 512, 2048] bf16 (x@W + bias)
    const u16* __restrict__ UT,   // [2048, 512] bf16 (U transposed)
    u16* __restrict__ hseq,       // [64, 512, 512] bf16
    u16* __restrict__ hbuf,       // [4][2][16][512] bf16
    u32* __restrict__ bar,        // [4][512]
    float* __restrict__ out_hT,   // [64,512] f32
    float* __restrict__ out_cT) { // [64,512] f32
  const int bi = blockIdx.x;
  const int g = (bi & 7) >> 1;                      // batch group
  const int wgi = ((bi & 1) << 2) | (bi >> 3);      // column wg 0..7
  const int tid = threadIdx.x;
  const int wave = tid >> 6;
  const int lane = tid & 63;
  const int n = lane & 15;
  const int q4 = lane >> 4;
  const int cb = wgi * 64 + wave * 16;              // h-col base of this wave

  __shared__ __align__(16) u16 hls[16 * 520];       // h_{t-1} staged, +8 pad

  // Preload U fragments: u[gate][ktile], B-operand layout B[n=lane&15][k=q4*8+j]
  bf16x8 u[4][16];
#pragma unroll
  for (int qg = 0; qg < 4; ++qg) {
    const u16* up = UT + (size_t)(qg * 512 + cb + n) * 512;
#pragma unroll
    for (int kt = 0; kt < 16; ++kt)
      u[qg][kt] = *(const bf16x8*)(up + kt * 32 + q4 * 8);
  }

  float cst[4] = {0.f, 0.f, 0.f, 0.f};
  const u16* xp_base = xp + (size_t)(g * 16) * T_STEPS * 2048;
  u32* barg = bar + g * T_STEPS;

#pragma unroll 1
  for (int t = 0; t < T_STEPS; ++t) {
    // x-projection loads: independent of h_{t-1}; issue before the spin
    float xpv[4][4];
#pragma unroll
    for (int qg = 0; qg < 4; ++qg)
#pragma unroll
      for (int r = 0; r < 4; ++r)
        xpv[qg][r] = bf2f(xp_base[((size_t)(q4 * 4 + r) * T_STEPS + t) * 2048
                                  + qg * 512 + cb + n]);

    floatx4 acc[4] = {};
    if (t > 0) {
      if (lane == 0) { // per-wave acquire spin
        while (__hip_atomic_load(barg + (t - 1), __ATOMIC_ACQUIRE,
                                 __HIP_MEMORY_SCOPE_AGENT) < 8u) { }
      }
      // stage h_{t-1} [16][512] -> LDS (coalesced 16B loads)
      const u16* hsrc = hbuf + (size_t)((g * 2 + ((t - 1) & 1)) * 16) * 512;
#pragma unroll
      for (int it = 0; it < 4; ++it) {
        int idx = (it * 256 + tid) * 8;
        int row = idx >> 9, col = idx & 511;
        *(short8*)(hls + row * 520 + col) = *(const short8*)(hsrc + idx);
      }
      __syncthreads();
#pragma unroll
      for (int kt = 0; kt < 16; ++kt) {
        bf16x8 a = *(const bf16x8*)(hls + n * 520 + kt * 32 + q4 * 8);
        acc[0] = __builtin_amdgcn_mfma_f32_16x16x32_bf16(a, u[0][kt], acc[0], 0, 0, 0);
        acc[1] = __builtin_amdgcn_mfma_f32_16x16x32_bf16(a, u[1][kt], acc[1], 0, 0, 0);
        acc[2] = __builtin_amdgcn_mfma_f32_16x16x32_bf16(a, u[2][kt], acc[2], 0, 0, 0);
        acc[3] = __builtin_amdgcn_mfma_f32_16x16x32_bf16(a, u[3][kt], acc[3], 0, 0, 0);
      }
    }

    // gates (C-layout: row = q4*4+r = batch, col = n = h-col), state update
    u16* hdst = hbuf + (size_t)((g * 2 + (t & 1)) * 16) * 512;
#pragma unroll
    for (int r = 0; r < 4; ++r) {
      float gi = sigm(acc[0][r] + xpv[0][r]);
      float gf = sigm(acc[1][r] + xpv[1][r]);
      float gg = tanh_f(acc[2][r] + xpv[2][r]);
      float go = sigm(acc[3][r] + xpv[3][r]);
      float cn = gf * cst[r] + gi * gg;
      cst[r] = cn;
      float hv = go * tanh_f(cn);
      u16 hb = f2bf(hv);
      int row = q4 * 4 + r;
      hdst[row * 512 + cb + n] = hb;
      hseq[((size_t)(g * 16 + row) * T_STEPS + t) * 512 + cb + n] = hb;
      if (t == T_STEPS - 1) {
        out_hT[(g * 16 + row) * 512 + cb + n] = hv;
        out_cT[(g * 16 + row) * 512 + cb + n] = cn;
      }
    }
    __threadfence();     // make h stores agent-visible
    __syncthreads();     // all waves of this wg done
    if (tid == 0)
      __hip_atomic_fetch_add(barg + t, 1u, __ATOMIC_RELEASE, __HIP_MEMORY_SCOPE_AGENT);
  }
}

// ---------- launch ----------
extern "C" void kernel_launch(void* const* d_in, const int* in_sizes, int n_in,
                              void* d_out, int out_size, void* d_ws, size_t ws_size,
                              hipStream_t stream) {
  (void)in_sizes; (void)n_in; (void)out_size; (void)ws_size;
  const float* x    = (const float*)d_in[0]; // [64,512,256] f32
  const float* W    = (const float*)d_in[1]; // [256,2048] f32
  const float* U    = (const float*)d_in[2]; // [512,2048] f32
  const float* bias = (const float*)d_in[3]; // [2048] f32
  const float* Wl   = (const float*)d_in[4]; // [512,256] f32
  const float* bl   = (const float*)d_in[5]; // [256] f32
  float* out = (float*)d_out;                // [64,512,256] ++ hT[64,512] ++ cT[64,512]
  char* ws = (char*)d_ws;

  u16* xp   = (u16*)(ws + 0);            // 134,217,728 B
  u16* UT   = (u16*)(ws + 134217728);    //   2,097,152 B
  u16* WT   = (u16*)(ws + 136314880);    //   1,048,576 B
  u16* WlT  = (u16*)(ws + 137363456);    //     262,144 B
  u16* hseq = (u16*)(ws + 137625600);    //  33,554,432 B
  u16* hbuf = (u16*)(ws + 171180032);    //     131,072 B
  u32* bar  = (u32*)(ws + 171311104);    //       8,192 B

  hipMemsetAsync(bar, 0, 4 * T_STEPS * sizeof(u32), stream);

  transpose_f32_bf16<<<dim3(2048 / 32, 256 / 32), dim3(32, 8), 0, stream>>>(W, WT, 256, 2048);
  transpose_f32_bf16<<<dim3(2048 / 32, 512 / 32), dim3(32, 8), 0, stream>>>(U, UT, 512, 2048);
  transpose_f32_bf16<<<dim3(256 / 32, 512 / 32), dim3(32, 8), 0, stream>>>(Wl, WlT, 512, 256);

  // x_proj = x @ W + bias : [32768,256] x [256,2048] -> bf16
  gemm_a32_bt<<<dim3(2048 / 64, 32768 / 64), 256, 0, stream>>>(x, WT, bias, xp, 32768, 2048, 256);

  // sequential LSTM scan
  lstm_scan<<<32, 256, 0, stream>>>(xp, UT, hseq, hbuf, bar,
                                    out + 8388608, out + 8421376);

  // out = hseq @ Wl + bl : [32768,512] x [512,256] -> f32
  gemm_bt_f32out<<<dim3(256 / 64, 32768 / 64), 256, 0, stream>>>(hseq, WlT, bl, out, 32768, 256, 512);
}

// Round 4
// 2438.975 us; speedup vs baseline: 1.7694x; 1.7694x over previous
//
#include <hip/hip_runtime.h>
#include <stdint.h>

typedef uint16_t u16;
typedef uint32_t u32;
typedef unsigned long long u64;
typedef __attribute__((ext_vector_type(8))) __bf16 bf16x8;
typedef __attribute__((ext_vector_type(8))) short short8;
typedef __attribute__((ext_vector_type(4))) float floatx4;

// ---------- helpers ----------
__device__ __forceinline__ float bf2f(u16 u) {
  union { u32 i; float f; } v; v.i = ((u32)u) << 16; return v.f;
}
__device__ __forceinline__ u16 f2bf(float f) {
  union { float f; u32 i; } v; v.f = f;
  u32 i = v.i;
  return (u16)((i + 0x7FFFu + ((i >> 16) & 1u)) >> 16); // RTNE
}
__device__ __forceinline__ float sigm(float x) { return 1.f / (1.f + __expf(-x)); }
__device__ __forceinline__ float tanh_f(float x) {
  x = fminf(15.f, fmaxf(-15.f, x));
  float e = __expf(2.f * x);
  return (e - 1.f) / (e + 1.f);
}

// ---------- fp32 -> bf16 transpose: src[R][C] f32 -> dst[C][R] bf16 ----------
__global__ void transpose_f32_bf16(const float* __restrict__ src, u16* __restrict__ dst,
                                   int R, int C) {
  __shared__ u16 tile[32][33];
  int x = blockIdx.x * 32 + threadIdx.x;
#pragma unroll
  for (int j = 0; j < 4; ++j) {
    int y = blockIdx.y * 32 + threadIdx.y + j * 8;
    if (x < C && y < R) tile[threadIdx.y + j * 8][threadIdx.x] = f2bf(src[(size_t)y * C + x]);
  }
  __syncthreads();
  int x2 = blockIdx.y * 32 + threadIdx.x;
#pragma unroll
  for (int j = 0; j < 4; ++j) {
    int y2 = blockIdx.x * 32 + threadIdx.y + j * 8;
    if (x2 < R && y2 < C) dst[(size_t)y2 * R + x2] = tile[threadIdx.x][threadIdx.y + j * 8];
  }
}

// ---------- xp GEMM: C_bf16[M,N] = A_f32[M,K] @ BT_bf16[N,K]^T + bias_f32 ----------
__global__ __launch_bounds__(256) void gemm_a32_bt(
    const float* __restrict__ A, const u16* __restrict__ BT,
    const float* __restrict__ bias, u16* __restrict__ C,
    int M, int N, int K) {
  __shared__ __align__(16) u16 As[64 * 40];
  __shared__ __align__(16) u16 Bs[64 * 40];
  const int tid = threadIdx.x;
  const int wave = tid >> 6, lane = tid & 63;
  const int q4 = lane >> 4, n16 = lane & 15;
  const int mw = (wave >> 1) * 32, nw = (wave & 1) * 32;
  const int m0 = blockIdx.y * 64, n0 = blockIdx.x * 64;
  const int ldrow = tid >> 2, ldseg = (tid & 3) * 8;

  floatx4 acc[2][2] = {};
  for (int k0 = 0; k0 < K; k0 += 32) {
    const float* ap = A + (size_t)(m0 + ldrow) * K + k0 + ldseg;
    floatx4 a0 = *(const floatx4*)ap;
    floatx4 a1 = *(const floatx4*)(ap + 4);
    short8 s;
    s[0] = (short)f2bf(a0[0]); s[1] = (short)f2bf(a0[1]);
    s[2] = (short)f2bf(a0[2]); s[3] = (short)f2bf(a0[3]);
    s[4] = (short)f2bf(a1[0]); s[5] = (short)f2bf(a1[1]);
    s[6] = (short)f2bf(a1[2]); s[7] = (short)f2bf(a1[3]);
    *(short8*)(As + ldrow * 40 + ldseg) = s;
    *(short8*)(Bs + ldrow * 40 + ldseg) =
        *(const short8*)(BT + (size_t)(n0 + ldrow) * K + k0 + ldseg);
    __syncthreads();
#pragma unroll
    for (int mi = 0; mi < 2; ++mi) {
      bf16x8 a = *(const bf16x8*)(As + (mw + mi * 16 + n16) * 40 + q4 * 8);
#pragma unroll
      for (int ni = 0; ni < 2; ++ni) {
        bf16x8 b = *(const bf16x8*)(Bs + (nw + ni * 16 + n16) * 40 + q4 * 8);
        acc[mi][ni] = __builtin_amdgcn_mfma_f32_16x16x32_bf16(a, b, acc[mi][ni], 0, 0, 0);
      }
    }
    __syncthreads();
  }
#pragma unroll
  for (int mi = 0; mi < 2; ++mi)
#pragma unroll
    for (int ni = 0; ni < 2; ++ni) {
      int col = n0 + nw + ni * 16 + n16;
      float bv = bias[col];
#pragma unroll
      for (int r = 0; r < 4; ++r) {
        int m = m0 + mw + mi * 16 + q4 * 4 + r;
        C[(size_t)m * N + col] = f2bf(acc[mi][ni][r] + bv);
      }
    }
}

// ---------- final GEMM over permuted hidden layout ----------
// A'[32768][512] where row m: g=m>>13, t=(m&8191)>>4, r=m&15  (hT_all layout)
// output row = (g*16+r)*512 + t   (reference [b][t] layout, b = g*16+r)
__global__ __launch_bounds__(256) void gemm_bt_f32out_perm(
    const u16* __restrict__ A, const u16* __restrict__ BT,
    const float* __restrict__ bias, float* __restrict__ C,
    int M, int N, int K) {
  __shared__ __align__(16) u16 As[64 * 40];
  __shared__ __align__(16) u16 Bs[64 * 40];
  const int tid = threadIdx.x;
  const int wave = tid >> 6, lane = tid & 63;
  const int q4 = lane >> 4, n16 = lane & 15;
  const int mw = (wave >> 1) * 32, nw = (wave & 1) * 32;
  const int m0 = blockIdx.y * 64, n0 = blockIdx.x * 64;
  const int ldrow = tid >> 2, ldseg = (tid & 3) * 8;

  floatx4 acc[2][2] = {};
  for (int k0 = 0; k0 < K; k0 += 32) {
    *(short8*)(As + ldrow * 40 + ldseg) =
        *(const short8*)(A + (size_t)(m0 + ldrow) * K + k0 + ldseg);
    *(short8*)(Bs + ldrow * 40 + ldseg) =
        *(const short8*)(BT + (size_t)(n0 + ldrow) * K + k0 + ldseg);
    __syncthreads();
#pragma unroll
    for (int mi = 0; mi < 2; ++mi) {
      bf16x8 a = *(const bf16x8*)(As + (mw + mi * 16 + n16) * 40 + q4 * 8);
#pragma unroll
      for (int ni = 0; ni < 2; ++ni) {
        bf16x8 b = *(const bf16x8*)(Bs + (nw + ni * 16 + n16) * 40 + q4 * 8);
        acc[mi][ni] = __builtin_amdgcn_mfma_f32_16x16x32_bf16(a, b, acc[mi][ni], 0, 0, 0);
      }
    }
    __syncthreads();
  }
#pragma unroll
  for (int mi = 0; mi < 2; ++mi)
#pragma unroll
    for (int ni = 0; ni < 2; ++ni) {
      int col = n0 + nw + ni * 16 + n16;
      float bv = bias[col];
#pragma unroll
      for (int r = 0; r < 4; ++r) {
        int m = m0 + mw + mi * 16 + q4 * 4 + r;
        int orow = ((m >> 13) * 16 + (m & 15)) * 512 + ((m & 8191) >> 4);
        C[(size_t)orow * N + col] = acc[mi][ni][r] + bv;
      }
    }
}

// ---------- LSTM scan — fence-free sync via relaxed agent atomics ----------
// 32 blocks x 256 threads. 4 batch groups x 8 column-wgs. U in VGPRs (64KB/wave).
// h transfer: per-step slots in hT_all, written/read with RELAXED agent-scope
// atomic u64 ops (bypass L1/L2 via sc flags, coherent at L3) -> zero
// cache-maintenance instructions on the critical path.
// Ordering: __syncthreads drains vmcnt(0) before the flag add; single coherence
// point makes "poll saw 8 => h stores visible to later loads" sound.
#define T_STEPS 512
__global__ __launch_bounds__(256, 1) void lstm_scan(
    const u16* __restrict__ xp,     // [64, 512, 2048] bf16
    const u16* __restrict__ UT,     // [2048, 512] bf16
    u16* __restrict__ hT_all,       // [4][512][16][512] bf16 (also final hidden seq)
    u32* __restrict__ bar,          // [4][512]
    float* __restrict__ out_hT,     // [64,512] f32
    float* __restrict__ out_cT) {   // [64,512] f32
  const int bi = blockIdx.x;
  const int g = (bi & 7) >> 1;
  const int wgi = ((bi & 1) << 2) | (bi >> 3);
  const int tid = threadIdx.x;
  const int wave = tid >> 6;
  const int lane = tid & 63;
  const int n = lane & 15;
  const int q4 = lane >> 4;
  const int cb0 = wgi * 64;            // block's h-col base
  const int cb = cb0 + wave * 16;      // wave's h-col base

  __shared__ __align__(16) u16 hls[16 * 520];  // h_{t-1} staged (A-operand side)
  __shared__ __align__(16) u16 hst[16 * 68];   // own h tile, for store transpose

  // Preload U fragments (B-operand layout), 256 VGPRs/wave
  bf16x8 u[4][16];
#pragma unroll
  for (int qg = 0; qg < 4; ++qg) {
    const u16* up = UT + (size_t)(qg * 512 + cb + n) * 512;
#pragma unroll
    for (int kt = 0; kt < 16; ++kt)
      u[qg][kt] = *(const bf16x8*)(up + kt * 32 + q4 * 8);
  }

  float cst[4] = {0.f, 0.f, 0.f, 0.f};
  const u16* xp_base = xp + (size_t)(g * 16) * T_STEPS * 2048;
  u32* barg = bar + g * T_STEPS;

#pragma unroll 1
  for (int t = 0; t < T_STEPS; ++t) {
    // xp loads: independent of h_{t-1}, issue before the wait
    float xpv[4][4];
#pragma unroll
    for (int qg = 0; qg < 4; ++qg)
#pragma unroll
      for (int r = 0; r < 4; ++r)
        xpv[qg][r] = bf2f(xp_base[((size_t)(q4 * 4 + r) * T_STEPS + t) * 2048
                                  + qg * 512 + cb + n]);

    floatx4 acc[4] = {};
    if (t > 0) {
      if (lane == 0) {  // wave-lockstep: whole wave stalls until lane0 exits
        while (__hip_atomic_load(barg + (t - 1), __ATOMIC_RELAXED,
                                 __HIP_MEMORY_SCOPE_AGENT) < 8u) { }
      }
      __asm__ volatile("" ::: "memory");
      // h_{t-1}: relaxed agent atomic u64 loads (coherence-point reads) -> LDS
      // row = 512 u16 = 128 u64  (round-3 bug was >>6 / &63)
      const u64* hsrc = (const u64*)(hT_all + (size_t)(g * T_STEPS + (t - 1)) * 16 * 512);
#pragma unroll
      for (int it = 0; it < 8; ++it) {
        int idx = it * 256 + tid;          // u64 index 0..2047
        u64 v = __hip_atomic_load(hsrc + idx, __ATOMIC_RELAXED, __HIP_MEMORY_SCOPE_AGENT);
        int row = idx >> 7, seg = idx & 127;
        *(u64*)(hls + row * 520 + seg * 4) = v;
      }
      __syncthreads();
#pragma unroll
      for (int kt = 0; kt < 16; ++kt) {
        bf16x8 a = *(const bf16x8*)(hls + n * 520 + kt * 32 + q4 * 8);
        acc[0] = __builtin_amdgcn_mfma_f32_16x16x32_bf16(a, u[0][kt], acc[0], 0, 0, 0);
        acc[1] = __builtin_amdgcn_mfma_f32_16x16x32_bf16(a, u[1][kt], acc[1], 0, 0, 0);
        acc[2] = __builtin_amdgcn_mfma_f32_16x16x32_bf16(a, u[2][kt], acc[2], 0, 0, 0);
        acc[3] = __builtin_amdgcn_mfma_f32_16x16x32_bf16(a, u[3][kt], acc[3], 0, 0, 0);
      }
    }

    // gates + state update (C-layout: row=q4*4+r, col=n within wave tile)
#pragma unroll
    for (int r = 0; r < 4; ++r) {
      float gi = sigm(acc[0][r] + xpv[0][r]);
      float gf = sigm(acc[1][r] + xpv[1][r]);
      float gg = tanh_f(acc[2][r] + xpv[2][r]);
      float go = sigm(acc[3][r] + xpv[3][r]);
      float cn = gf * cst[r] + gi * gg;
      cst[r] = cn;
      float hv = go * tanh_f(cn);
      u16 hb = f2bf(hv);
      int row = q4 * 4 + r;
      hst[row * 68 + wave * 16 + n] = hb;   // LDS transpose staging
      if (t == T_STEPS - 1) {
        out_hT[(g * 16 + row) * 512 + cb + n] = hv;
        out_cT[(g * 16 + row) * 512 + cb + n] = cn;
      }
    }
    __syncthreads();  // hst tile complete

    // write own 16x64 h-tile, row-major coalesced u64 relaxed agent atomic stores
    {
      int row = tid >> 4, seg = tid & 15;
      u64 v = *(const u64*)(hst + row * 68 + seg * 4);
      u64* hdst = (u64*)(hT_all + (size_t)(g * T_STEPS + t) * 16 * 512);
      __hip_atomic_store(hdst + row * 128 + (cb0 >> 2) + seg, v,
                         __ATOMIC_RELAXED, __HIP_MEMORY_SCOPE_AGENT);
    }
    __syncthreads();  // drains vmcnt(0) per thread -> all h stores at coherence point
    if (tid == 0)
      __hip_atomic_fetch_add(barg + t, 1u, __ATOMIC_RELAXED, __HIP_MEMORY_SCOPE_AGENT);
  }
}

// ---------- launch ----------
extern "C" void kernel_launch(void* const* d_in, const int* in_sizes, int n_in,
                              void* d_out, int out_size, void* d_ws, size_t ws_size,
                              hipStream_t stream) {
  (void)in_sizes; (void)n_in; (void)out_size; (void)ws_size;
  const float* x    = (const float*)d_in[0]; // [64,512,256] f32
  const float* W    = (const float*)d_in[1]; // [256,2048] f32
  const float* U    = (const float*)d_in[2]; // [512,2048] f32
  const float* bias = (const float*)d_in[3]; // [2048] f32
  const float* Wl   = (const float*)d_in[4]; // [512,256] f32
  const float* bl   = (const float*)d_in[5]; // [256] f32
  float* out = (float*)d_out;                // [64,512,256] ++ hT[64,512] ++ cT[64,512]
  char* ws = (char*)d_ws;

  u16* xp     = (u16*)(ws + 0);            // 134,217,728 B
  u16* UT     = (u16*)(ws + 134217728);    //   2,097,152 B
  u16* WT     = (u16*)(ws + 136314880);    //   1,048,576 B
  u16* WlT    = (u16*)(ws + 137363456);    //     262,144 B
  u16* hT_all = (u16*)(ws + 137625600);    //  33,554,432 B  [4][512][16][512]
  u32* bar    = (u32*)(ws + 171180032);    //       8,192 B

  hipMemsetAsync(bar, 0, 4 * T_STEPS * sizeof(u32), stream);

  transpose_f32_bf16<<<dim3(2048 / 32, 256 / 32), dim3(32, 8), 0, stream>>>(W, WT, 256, 2048);
  transpose_f32_bf16<<<dim3(2048 / 32, 512 / 32), dim3(32, 8), 0, stream>>>(U, UT, 512, 2048);
  transpose_f32_bf16<<<dim3(256 / 32, 512 / 32), dim3(32, 8), 0, stream>>>(Wl, WlT, 512, 256);

  // x_proj = x @ W + bias : [32768,256] x [256,2048] -> bf16
  gemm_a32_bt<<<dim3(2048 / 64, 32768 / 64), 256, 0, stream>>>(x, WT, bias, xp, 32768, 2048, 256);

  // sequential LSTM scan (writes hT_all in [g][t][r][col] layout)
  lstm_scan<<<32, 256, 0, stream>>>(xp, UT, hT_all, bar,
                                    out + 8388608, out + 8421376);

  // out = hseq @ Wl + bl, reading permuted layout, remapping output rows
  gemm_bt_f32out_perm<<<dim3(256 / 64, 32768 / 64), 256, 0, stream>>>(
      hT_all, WlT, bl, out, 32768, 256, 512);
}